// Round 1
// baseline (1595.053 us; speedup 1.0000x reference)
//
#include <hip/hip_runtime.h>

typedef __attribute__((ext_vector_type(8))) short short8;
typedef __attribute__((ext_vector_type(4))) float floatx4;

#define DEV __device__ __forceinline__

DEV void async_ld16(const void* g, void* l) {
  __builtin_amdgcn_global_load_lds(
      (const __attribute__((address_space(1))) unsigned int*)g,
      (__attribute__((address_space(3))) unsigned int*)l,
      16, 0, 0);
}

DEV unsigned short f2bf(float x) {
  union { float f; unsigned int u; } v; v.f = x;
  unsigned int u = v.u;
  u += 0x7FFFu + ((u >> 16) & 1u);   // round-to-nearest-even
  return (unsigned short)(u >> 16);
}

// ---------------------------------------------------------------------------
// Weight transform: conv_w fp32 [O][C][3][3][3] -> bf16 [tap][o][c]  (B^T)
// ---------------------------------------------------------------------------
__global__ void wtrans(const float* __restrict__ w, unsigned short* __restrict__ wt,
                       int total /* = O*C */) {
  int idx = blockIdx.x * 256 + threadIdx.x;
  if (idx >= total) return;
  const float* src = w + (long)idx * 27;
  #pragma unroll
  for (int tap = 0; tap < 27; ++tap)
    wt[(size_t)tap * total + idx] = f2bf(src[tap]);
}

// ---------------------------------------------------------------------------
// Build P1: videos fp32 [8][1024][14][14] -> P1 bf16 [t=8][s=6][16][16][1024]
// P1[t][s][h+1][w+1][c] = videos[t-5+s][c][h][w] for s in 1..4 (else zero).
// Grid: (frame 0..7, cchunk 0..15), block 256. LDS transpose (c,hw)->(hw,c).
// ---------------------------------------------------------------------------
__global__ void build_P1(const float* __restrict__ videos, unsigned short* __restrict__ P1) {
  const int f  = blockIdx.x;
  const int c0 = blockIdx.y * 64;
  const int tid = threadIdx.x;
  __shared__ unsigned short tile[64][196];

  #pragma unroll 1
  for (int it = 0; it < 49; ++it) {       // 49*256 = 64*196 exactly
    int idx = it * 256 + tid;
    int c = idx / 196, r = idx - c * 196;
    tile[c][r] = f2bf(videos[(size_t)(f * 1024 + c0 + c) * 196 + r]);
  }
  __syncthreads();

  const int c   = tid & 63;
  const int hwq = tid >> 6;
  #pragma unroll 1
  for (int s = 1; s <= 4; ++s) {
    int t = f + 5 - s;
    if (t > 7) continue;                  // t >= 0 always (s<=4 => t>=f+1>=1... f>=0)
    unsigned short* dst = P1 + (size_t)(t * 6 + s) * 256 * 1024 + (size_t)c0;
    #pragma unroll 1
    for (int it = 0; it < 49; ++it) {
      int hw = it * 4 + hwq;
      int h = hw / 14, w = hw - h * 14;
      dst[(size_t)((h + 1) * 16 + (w + 1)) * 1024 + c] = tile[c][hw];
    }
  }
}

// ---------------------------------------------------------------------------
// Implicit-GEMM conv, m97 structure: 128x128 tile, BK=64, global_load_lds x16,
// mfma_f32_16x16x32_bf16, fused bias+ReLU epilogue.
// A: padded input P [8][6][16][16][CIN] bf16 (rows = output positions)
// B: Wt [27][COUT][CIN] bf16 (B^T: k-contiguous per o-row)
// ---------------------------------------------------------------------------
template <int CIN, int COUT, bool WRITE_P2>
__global__ __launch_bounds__(256) void conv_gemm(
    const unsigned short* __restrict__ P,
    const unsigned short* __restrict__ Wt,
    const float* __restrict__ bias,
    unsigned short* __restrict__ P2out,   // [8][6][16][16][COUT] (interior) if WRITE_P2
    float* __restrict__ h2out)            // [6272][COUT] otherwise
{
  __shared__ short lA[128 * 64];
  __shared__ short lB[128 * 64];
  const int tid  = threadIdx.x;
  const int wave = tid >> 6;
  const int lane = tid & 63;
  const int m0 = blockIdx.x * 128;
  const int n0 = blockIdx.y * 128;

  // Staging assignment: segment s_i = i*256 + tid; row = s_i>>3; 16B col = tid&7.
  const int rb   = tid >> 3;
  const int segb = (tid & 7) * 16;
  int aoff[4], boff[4];
  #pragma unroll
  for (int i = 0; i < 4; ++i) {
    int r = i * 32 + rb;
    int m = m0 + r;
    int t = m / 784;  int r2 = m - t * 784;
    int d = r2 / 196; int r3 = r2 - d * 196;
    int h = r3 / 14;  int w = r3 - h * 14;
    aoff[i] = ((((t * 6 + d) * 16 + h) * 16 + w) * CIN) * 2 + segb;  // tap-separable base
    boff[i] = ((n0 + r) * CIN) * 2 + segb;
  }

  floatx4 acc[4][4];
  const floatx4 zero = {0.f, 0.f, 0.f, 0.f};
  #pragma unroll
  for (int i = 0; i < 4; ++i)
    #pragma unroll
    for (int j = 0; j < 4; ++j) acc[i][j] = zero;

  const char* Pb = (const char*)P;
  const char* Wb = (const char*)Wt;
  const int wm = (wave >> 1) * 64;
  const int wn = (wave & 1) * 64;
  const int quad = lane >> 4;
  const int l15  = lane & 15;

  #pragma unroll 1
  for (int tap = 0; tap < 27; ++tap) {
    const int kd = tap / 9; const int rem = tap - kd * 9;
    const int kh = rem / 3; const int kw = rem - kh * 3;
    const int tapA = (((kd * 16) + kh) * 16 + kw) * CIN * 2;
    const int tapB = tap * COUT * CIN * 2;
    #pragma unroll 1
    for (int c0 = 0; c0 < CIN; c0 += 64) {
      const int cb = c0 * 2;
      __syncthreads();
      #pragma unroll
      for (int i = 0; i < 4; ++i)
        async_ld16(Pb + (aoff[i] + tapA + cb), (char*)lA + (i * 256 + tid) * 16);
      #pragma unroll
      for (int i = 0; i < 4; ++i)
        async_ld16(Wb + (boff[i] + tapB + cb), (char*)lB + (i * 256 + tid) * 16);
      __syncthreads();
      #pragma unroll
      for (int ks = 0; ks < 2; ++ks) {
        short8 a[4], b[4];
        #pragma unroll
        for (int i = 0; i < 4; ++i)
          a[i] = *(const short8*)(lA + (wm + i * 16 + l15) * 64 + ks * 32 + quad * 8);
        #pragma unroll
        for (int j = 0; j < 4; ++j)
          b[j] = *(const short8*)(lB + (wn + j * 16 + l15) * 64 + ks * 32 + quad * 8);
        #pragma unroll
        for (int i = 0; i < 4; ++i)
          #pragma unroll
          for (int j = 0; j < 4; ++j)
            acc[i][j] = __builtin_amdgcn_mfma_f32_16x16x32_bf16(a[i], b[j], acc[i][j], 0, 0, 0);
      }
    }
  }

  // Epilogue: C/D layout col=lane&15, row=quad*4+reg (m89/m91-verified).
  #pragma unroll
  for (int j = 0; j < 4; ++j) {
    const int o = n0 + wn + j * 16 + l15;
    const float bv = bias[o];
    #pragma unroll
    for (int i = 0; i < 4; ++i) {
      #pragma unroll
      for (int r = 0; r < 4; ++r) {
        int m = m0 + wm + i * 16 + quad * 4 + r;
        float v = acc[i][j][r] + bv;
        v = v > 0.f ? v : 0.f;
        if (WRITE_P2) {
          int t = m / 784;  int r2 = m - t * 784;
          int d = r2 / 196; int r3 = r2 - d * 196;
          int h = r3 / 14;  int w = r3 - h * 14;
          P2out[(size_t)(((t * 6 + d + 1) * 16 + (h + 1)) * 16 + (w + 1)) * COUT + o] = f2bf(v);
        } else {
          h2out[(size_t)m * COUT + o] = v;
        }
      }
    }
  }
}

// ---------------------------------------------------------------------------
// Max-pool over 784 positions per (t, o). h2: [t*784+dhw][512] fp32, relu'd (>=0).
// ---------------------------------------------------------------------------
__global__ void pool_kernel(const float* __restrict__ h2, float* __restrict__ pooled) {
  int t = blockIdx.x, o = threadIdx.x;   // 512 threads
  const float* src = h2 + (size_t)t * 784 * 512 + o;
  float m = 0.f;
  #pragma unroll 4
  for (int i = 0; i < 784; ++i) m = fmaxf(m, src[(size_t)i * 512]);
  pooled[t * 512 + o] = m;
}

// ---------------------------------------------------------------------------
// Tiny MLP, fp32. Block per t, 512 threads.
// ---------------------------------------------------------------------------
__global__ void mlp_kernel(const float* __restrict__ pooled,
                           const float* __restrict__ w1, const float* __restrict__ b1,
                           const float* __restrict__ w2, const float* __restrict__ b2,
                           const float* __restrict__ w3, const float* __restrict__ b3,
                           float* __restrict__ out) {
  const int t = blockIdx.x, j = threadIdx.x;
  __shared__ float xa[512], xb[512];
  xa[j] = pooled[t * 512 + j];
  __syncthreads();
  {
    const float4* wr = (const float4*)(w1 + (size_t)j * 512);
    float s = b1[j];
    #pragma unroll 4
    for (int k = 0; k < 128; ++k) {
      float4 wv = wr[k];
      s += wv.x * xa[4*k] + wv.y * xa[4*k+1] + wv.z * xa[4*k+2] + wv.w * xa[4*k+3];
    }
    xb[j] = fmaxf(s, 0.f);
  }
  __syncthreads();
  {
    const float4* wr = (const float4*)(w2 + (size_t)j * 512);
    float s = b2[j];
    #pragma unroll 4
    for (int k = 0; k < 128; ++k) {
      float4 wv = wr[k];
      s += wv.x * xb[4*k] + wv.y * xb[4*k+1] + wv.z * xb[4*k+2] + wv.w * xb[4*k+3];
    }
    xa[j] = fmaxf(s, 0.f);
  }
  __syncthreads();
  if (j < 128) {
    const float4* wr = (const float4*)(w3 + (size_t)j * 512);
    float s = b3[j];
    #pragma unroll 4
    for (int k = 0; k < 128; ++k) {
      float4 wv = wr[k];
      s += wv.x * xa[4*k] + wv.y * xa[4*k+1] + wv.z * xa[4*k+2] + wv.w * xa[4*k+3];
    }
    out[t * 128 + j] = fmaxf(s, 0.f);
  }
}

// ---------------------------------------------------------------------------
// Workspace layout (bytes):
//   P1   @ 0          : 8*6*16*16*1024*2 = 25,165,824
//   P2   @ 25165824   : 25,165,824
//   W1t  @ 50331648   : 27*1024*1024*2 = 56,623,104
//   W2t  @ 106954752  : 27*512*1024*2  = 28,311,552
//   h2   @ 135266304  : 6272*512*4     = 12,845,056
//   pool @ 148111360  : 8*512*4        = 16,384        -> total ~148.1 MB
// ---------------------------------------------------------------------------
extern "C" void kernel_launch(void* const* d_in, const int* in_sizes, int n_in,
                              void* d_out, int out_size, void* d_ws, size_t ws_size,
                              hipStream_t stream) {
  const float* videos = (const float*)d_in[0];
  const float* c1w = (const float*)d_in[1];
  const float* c1b = (const float*)d_in[2];
  const float* c2w = (const float*)d_in[3];
  const float* c2b = (const float*)d_in[4];
  const float* l1w = (const float*)d_in[5];
  const float* l1b = (const float*)d_in[6];
  const float* l2w = (const float*)d_in[7];
  const float* l2b = (const float*)d_in[8];
  const float* l3w = (const float*)d_in[9];
  const float* l3b = (const float*)d_in[10];

  char* ws = (char*)d_ws;
  unsigned short* P1  = (unsigned short*)(ws);
  unsigned short* P2  = (unsigned short*)(ws + 25165824);
  unsigned short* W1t = (unsigned short*)(ws + 50331648);
  unsigned short* W2t = (unsigned short*)(ws + 106954752);
  float* h2     = (float*)(ws + 135266304);
  float* pooled = (float*)(ws + 148111360);
  float* out = (float*)d_out;

  // Zero padded activation buffers (halo + unused windows must be 0).
  hipMemsetAsync(ws, 0, 50331648, stream);

  wtrans<<<4096, 256, 0, stream>>>(c1w, W1t, 1024 * 1024);
  wtrans<<<2048, 256, 0, stream>>>(c2w, W2t, 512 * 1024);
  build_P1<<<dim3(8, 16), 256, 0, stream>>>(videos, P1);

  conv_gemm<1024, 1024, true ><<<dim3(49, 8), 256, 0, stream>>>(P1, W1t, c1b, P2, nullptr);
  conv_gemm<1024, 512, false><<<dim3(49, 4), 256, 0, stream>>>(P2, W2t, c2b, nullptr, h2);

  pool_kernel<<<8, 512, 0, stream>>>(h2, pooled);
  mlp_kernel<<<8, 512, 0, stream>>>(pooled, l1w, l1b, l2w, l2b, l3w, l3b, out);
}

// Round 2
// 1209.543 us; speedup vs baseline: 1.3187x; 1.3187x over previous
//
#include <hip/hip_runtime.h>

typedef __attribute__((ext_vector_type(8))) short short8;
typedef __attribute__((ext_vector_type(4))) float floatx4;
typedef __attribute__((ext_vector_type(4))) unsigned short ushort4v;

#define DEV __device__ __forceinline__

constexpr int M_TOT = 6272;   // 8 * 784 output positions

DEV void async_ld16(const void* g, void* l) {
  __builtin_amdgcn_global_load_lds(
      (const __attribute__((address_space(1))) unsigned int*)g,
      (__attribute__((address_space(3))) unsigned int*)l,
      16, 0, 0);
}

DEV unsigned short f2bf(float x) {
  union { float f; unsigned int u; } v; v.f = x;
  unsigned int u = v.u;
  u += 0x7FFFu + ((u >> 16) & 1u);   // round-to-nearest-even
  return (unsigned short)(u >> 16);
}

DEV float bf2f(unsigned short s) {
  union { unsigned int u; float f; } v; v.u = ((unsigned int)s) << 16;
  return v.f;
}

// ---------------------------------------------------------------------------
// Weight transform: conv_w fp32 [O][C][3][3][3] -> bf16 [tap][o][c]  (B^T)
// ---------------------------------------------------------------------------
__global__ void wtrans(const float* __restrict__ w, unsigned short* __restrict__ wt,
                       int total /* = O*C */) {
  int idx = blockIdx.x * 256 + threadIdx.x;
  if (idx >= total) return;
  const float* src = w + (long)idx * 27;
  #pragma unroll
  for (int tap = 0; tap < 27; ++tap)
    wt[(size_t)tap * total + idx] = f2bf(src[tap]);
}

// ---------------------------------------------------------------------------
// Build P1: videos fp32 [8][1024][14][14] -> P1 bf16 [t=8][s=6][16][16][1024]
// P1[t][s][h+1][w+1][c] = videos[t-5+s][c][h][w] for s in 1..4 (else zero).
// ---------------------------------------------------------------------------
__global__ void build_P1(const float* __restrict__ videos, unsigned short* __restrict__ P1) {
  const int f  = blockIdx.x;
  const int c0 = blockIdx.y * 64;
  const int tid = threadIdx.x;
  __shared__ unsigned short tile[64][196];

  #pragma unroll 1
  for (int it = 0; it < 49; ++it) {       // 49*256 = 64*196 exactly
    int idx = it * 256 + tid;
    int c = idx / 196, r = idx - c * 196;
    tile[c][r] = f2bf(videos[(size_t)(f * 1024 + c0 + c) * 196 + r]);
  }
  __syncthreads();

  const int c   = tid & 63;
  const int hwq = tid >> 6;
  #pragma unroll 1
  for (int s = 1; s <= 4; ++s) {
    int t = f + 5 - s;
    if (t > 7) continue;
    unsigned short* dst = P1 + (size_t)(t * 6 + s) * 256 * 1024 + (size_t)c0;
    #pragma unroll 1
    for (int it = 0; it < 49; ++it) {
      int hw = it * 4 + hwq;
      int h = hw / 14, w = hw - h * 14;
      dst[(size_t)((h + 1) * 16 + (w + 1)) * 1024 + c] = tile[c][hw];
    }
  }
}

// ---------------------------------------------------------------------------
// Implicit-GEMM conv, split-K over taps. 128x128 tile, BK=64, global_load_lds
// x16 with XOR-swizzled segment fetch (kills the 16-way LDS read conflicts),
// mfma_f32_16x16x32_bf16. Writes bf16 partial sums (no bias/relu).
// A: padded input P [8][6][16][16][CIN] bf16;  B: Wt [27][COUT][CIN] bf16.
// grid (49, COUT/128, SLICES)
// ---------------------------------------------------------------------------
template <int CIN, int COUT, int SLICES>
__global__ __launch_bounds__(256) void conv_gemm(
    const unsigned short* __restrict__ P,
    const unsigned short* __restrict__ Wt,
    unsigned short* __restrict__ part)
{
  __shared__ short lA[128 * 64];
  __shared__ short lB[128 * 64];
  const int tid  = threadIdx.x;
  const int wave = tid >> 6;
  const int lane = tid & 63;
  const int m0 = blockIdx.x * 128;
  const int n0 = blockIdx.y * 128;
  const int z  = blockIdx.z;
  const int tap0 = (27 * z) / SLICES;
  const int tap1 = (27 * (z + 1)) / SLICES;
  unsigned short* partOut = part + (size_t)z * M_TOT * COUT;

  // Staging: LDS segment s_i = i*256+tid (16B units); row r = s_i>>3.
  // XOR swizzle: fetch global segment (tid&7) ^ (r&7) so fragment reads
  // land on distinct bank groups.
  const int rb   = tid >> 3;
  const int segb = (((tid & 7) ^ (rb & 7)) * 16);
  int aoff[4], boff[4];
  #pragma unroll
  for (int i = 0; i < 4; ++i) {
    int r = i * 32 + rb;
    int m = m0 + r;
    int t = m / 784;  int r2 = m - t * 784;
    int d = r2 / 196; int r3 = r2 - d * 196;
    int h = r3 / 14;  int w = r3 - h * 14;
    aoff[i] = ((((t * 6 + d) * 16 + h) * 16 + w) * CIN) * 2 + segb;  // tap-separable
    boff[i] = ((n0 + r) * CIN) * 2 + segb;
  }

  floatx4 acc[4][4];
  const floatx4 zero = {0.f, 0.f, 0.f, 0.f};
  #pragma unroll
  for (int i = 0; i < 4; ++i)
    #pragma unroll
    for (int j = 0; j < 4; ++j) acc[i][j] = zero;

  const char* Pb = (const char*)P;
  const char* Wb = (const char*)Wt;
  const int wm = (wave >> 1) * 64;
  const int wn = (wave & 1) * 64;
  const int quad = lane >> 4;
  const int l15  = lane & 15;
  const int xorv = l15 & 7;

  #pragma unroll 1
  for (int tap = tap0; tap < tap1; ++tap) {
    const int kd = tap / 9; const int rem = tap - kd * 9;
    const int kh = rem / 3; const int kw = rem - kh * 3;
    const int tapA = (((kd * 16) + kh) * 16 + kw) * CIN * 2;
    const int tapB = tap * COUT * CIN * 2;
    #pragma unroll 1
    for (int c0 = 0; c0 < CIN; c0 += 64) {
      const int cb = c0 * 2;
      __syncthreads();
      #pragma unroll
      for (int i = 0; i < 4; ++i)
        async_ld16(Pb + (aoff[i] + tapA + cb), (char*)lA + (i * 256 + tid) * 16);
      #pragma unroll
      for (int i = 0; i < 4; ++i)
        async_ld16(Wb + (boff[i] + tapB + cb), (char*)lB + (i * 256 + tid) * 16);
      __syncthreads();
      #pragma unroll
      for (int ks = 0; ks < 2; ++ks) {
        short8 a[4], b[4];
        #pragma unroll
        for (int i = 0; i < 4; ++i)
          a[i] = *(const short8*)(lA + (wm + i * 16 + l15) * 64 + ((ks * 4 + quad) ^ xorv) * 8);
        #pragma unroll
        for (int j = 0; j < 4; ++j)
          b[j] = *(const short8*)(lB + (wn + j * 16 + l15) * 64 + ((ks * 4 + quad) ^ xorv) * 8);
        #pragma unroll
        for (int i = 0; i < 4; ++i)
          #pragma unroll
          for (int j = 0; j < 4; ++j)
            acc[i][j] = __builtin_amdgcn_mfma_f32_16x16x32_bf16(a[i], b[j], acc[i][j], 0, 0, 0);
      }
    }
  }

  // Epilogue: C/D layout col=lane&15, row=quad*4+reg. Raw bf16 partials.
  #pragma unroll
  for (int j = 0; j < 4; ++j) {
    const int o = n0 + wn + j * 16 + l15;
    #pragma unroll
    for (int i = 0; i < 4; ++i) {
      #pragma unroll
      for (int r = 0; r < 4; ++r) {
        int m = m0 + wm + i * 16 + quad * 4 + r;
        partOut[(size_t)m * COUT + o] = f2bf(acc[i][j][r]);
      }
    }
  }
}

// ---------------------------------------------------------------------------
// reduce1: sum 2 bf16 partial slices + bias, relu, cast bf16, scatter into
// padded P2 layout [8][6][16][16][1024] (interior only; halo pre-zeroed).
// grid 6272 blocks x 256 thr; thread handles 4 consecutive o.
// ---------------------------------------------------------------------------
__global__ void reduce_conv1(const unsigned short* __restrict__ part,
                             const float* __restrict__ bias,
                             unsigned short* __restrict__ P2) {
  const int idx = blockIdx.x * 256 + threadIdx.x;
  const int m  = idx >> 8;
  const int o4 = (idx & 255) * 4;
  const size_t base = (size_t)m * 1024 + o4;
  ushort4v p0 = *(const ushort4v*)(part + base);
  ushort4v p1 = *(const ushort4v*)(part + (size_t)M_TOT * 1024 + base);
  ushort4v out;
  #pragma unroll
  for (int k = 0; k < 4; ++k) {
    float v = bf2f(p0[k]) + bf2f(p1[k]) + bias[o4 + k];
    out[k] = f2bf(v > 0.f ? v : 0.f);
  }
  int t = m / 784;  int r2 = m - t * 784;
  int d = r2 / 196; int r3 = r2 - d * 196;
  int h = r3 / 14;  int w = r3 - h * 14;
  size_t didx = (size_t)(((t * 6 + d + 1) * 16 + (h + 1)) * 16 + (w + 1)) * 1024 + o4;
  *(ushort4v*)(P2 + didx) = out;
}

// ---------------------------------------------------------------------------
// reduce2: sum 4 bf16 partial slices + bias, relu, cast bf16 -> h2 [6272][512].
// grid 3136 x 256; thread handles 4 consecutive o.
// ---------------------------------------------------------------------------
__global__ void reduce_conv2(const unsigned short* __restrict__ part,
                             const float* __restrict__ bias,
                             unsigned short* __restrict__ h2) {
  const int idx = blockIdx.x * 256 + threadIdx.x;
  const int m  = idx >> 7;
  const int o4 = (idx & 127) * 4;
  const size_t base = (size_t)m * 512 + o4;
  const size_t ss = (size_t)M_TOT * 512;
  ushort4v p0 = *(const ushort4v*)(part + base);
  ushort4v p1 = *(const ushort4v*)(part + ss + base);
  ushort4v p2 = *(const ushort4v*)(part + 2 * ss + base);
  ushort4v p3 = *(const ushort4v*)(part + 3 * ss + base);
  ushort4v out;
  #pragma unroll
  for (int k = 0; k < 4; ++k) {
    float v = bf2f(p0[k]) + bf2f(p1[k]) + bf2f(p2[k]) + bf2f(p3[k]) + bias[o4 + k];
    out[k] = f2bf(v > 0.f ? v : 0.f);
  }
  *(ushort4v*)(h2 + base) = out;
}

// ---------------------------------------------------------------------------
// Max-pool: h2 bf16 [6272][512], values >= 0 so bf16 bit pattern is monotone
// -> max over raw ushorts. Block per t, 512 threads (one o each).
// ---------------------------------------------------------------------------
__global__ void pool_kernel(const unsigned short* __restrict__ h2, float* __restrict__ pooled) {
  int t = blockIdx.x, o = threadIdx.x;
  const unsigned short* src = h2 + (size_t)t * 784 * 512 + o;
  unsigned short m = 0;
  #pragma unroll 4
  for (int i = 0; i < 784; ++i) { unsigned short v = src[(size_t)i * 512]; m = v > m ? v : m; }
  pooled[t * 512 + o] = bf2f(m);
}

// ---------------------------------------------------------------------------
// Tiny MLP, fp32. Block per t, 512 threads.
// ---------------------------------------------------------------------------
__global__ void mlp_kernel(const float* __restrict__ pooled,
                           const float* __restrict__ w1, const float* __restrict__ b1,
                           const float* __restrict__ w2, const float* __restrict__ b2,
                           const float* __restrict__ w3, const float* __restrict__ b3,
                           float* __restrict__ out) {
  const int t = blockIdx.x, j = threadIdx.x;
  __shared__ float xa[512], xb[512];
  xa[j] = pooled[t * 512 + j];
  __syncthreads();
  {
    const float4* wr = (const float4*)(w1 + (size_t)j * 512);
    float s = b1[j];
    #pragma unroll 4
    for (int k = 0; k < 128; ++k) {
      float4 wv = wr[k];
      s += wv.x * xa[4*k] + wv.y * xa[4*k+1] + wv.z * xa[4*k+2] + wv.w * xa[4*k+3];
    }
    xb[j] = fmaxf(s, 0.f);
  }
  __syncthreads();
  {
    const float4* wr = (const float4*)(w2 + (size_t)j * 512);
    float s = b2[j];
    #pragma unroll 4
    for (int k = 0; k < 128; ++k) {
      float4 wv = wr[k];
      s += wv.x * xb[4*k] + wv.y * xb[4*k+1] + wv.z * xb[4*k+2] + wv.w * xb[4*k+3];
    }
    xa[j] = fmaxf(s, 0.f);
  }
  __syncthreads();
  if (j < 128) {
    const float4* wr = (const float4*)(w3 + (size_t)j * 512);
    float s = b3[j];
    #pragma unroll 4
    for (int k = 0; k < 128; ++k) {
      float4 wv = wr[k];
      s += wv.x * xa[4*k] + wv.y * xa[4*k+1] + wv.z * xa[4*k+2] + wv.w * xa[4*k+3];
    }
    out[t * 128 + j] = fmaxf(s, 0.f);
  }
}

// ---------------------------------------------------------------------------
// Workspace layout (bytes) — total 142,229,504 (< 148.1 MB proven in R1):
//   P1/P2 (aliased) @ 0          : 8*6*16*16*1024*2 = 25,165,824
//   W1t             @ 25165824   : 27*1024*1024*2   = 56,623,104
//   W2t             @ 81788928   : 27*512*1024*2    = 28,311,552
//   part (reused)   @ 110100480  : 2*6272*1024*2 == 4*6272*512*2 = 25,690,112
//   h2 bf16         @ 135790592  : 6272*512*2       =  6,422,528
//   pooled          @ 142213120  : 8*512*4          =     16,384
// P2 aliases P1: reduce1 overwrites exactly P1's nonzero interior; the
// zeroed halo (memset) serves both convs. part reused conv1->conv2 (stream-
// ordered). h2 stored bf16 (>=0 after relu) so pool can max raw ushorts.
// ---------------------------------------------------------------------------
extern "C" void kernel_launch(void* const* d_in, const int* in_sizes, int n_in,
                              void* d_out, int out_size, void* d_ws, size_t ws_size,
                              hipStream_t stream) {
  const float* videos = (const float*)d_in[0];
  const float* c1w = (const float*)d_in[1];
  const float* c1b = (const float*)d_in[2];
  const float* c2w = (const float*)d_in[3];
  const float* c2b = (const float*)d_in[4];
  const float* l1w = (const float*)d_in[5];
  const float* l1b = (const float*)d_in[6];
  const float* l2w = (const float*)d_in[7];
  const float* l2b = (const float*)d_in[8];
  const float* l3w = (const float*)d_in[9];
  const float* l3b = (const float*)d_in[10];

  char* ws = (char*)d_ws;
  unsigned short* P12 = (unsigned short*)(ws);               // P1, later P2
  unsigned short* W1t = (unsigned short*)(ws + 25165824);
  unsigned short* W2t = (unsigned short*)(ws + 81788928);
  unsigned short* part = (unsigned short*)(ws + 110100480);
  unsigned short* h2  = (unsigned short*)(ws + 135790592);
  float* pooled = (float*)(ws + 142213120);
  float* out = (float*)d_out;

  // Zero the padded activation buffer (halo + unused windows must be 0).
  hipMemsetAsync(ws, 0, 25165824, stream);

  wtrans<<<4096, 256, 0, stream>>>(c1w, W1t, 1024 * 1024);
  wtrans<<<2048, 256, 0, stream>>>(c2w, W2t, 512 * 1024);
  build_P1<<<dim3(8, 16), 256, 0, stream>>>(videos, P12);

  conv_gemm<1024, 1024, 2><<<dim3(49, 8, 2), 256, 0, stream>>>(P12, W1t, part);
  reduce_conv1<<<6272, 256, 0, stream>>>(part, c1b, P12);
  conv_gemm<1024, 512, 4><<<dim3(49, 4, 4), 256, 0, stream>>>(P12, W2t, part);
  reduce_conv2<<<3136, 256, 0, stream>>>(part, c2b, h2);

  pool_kernel<<<8, 512, 0, stream>>>(h2, pooled);
  mlp_kernel<<<8, 512, 0, stream>>>(pooled, l1w, l1b, l2w, l2b, l3w, l3b, out);
}

// Round 4
// 1044.000 us; speedup vs baseline: 1.5278x; 1.1586x over previous
//
#include <hip/hip_runtime.h>

typedef __attribute__((ext_vector_type(8))) short short8;
typedef __attribute__((ext_vector_type(4))) float floatx4;
typedef __attribute__((ext_vector_type(4))) unsigned short ushort4v;

#define DEV __device__ __forceinline__

constexpr int M_TOT = 6272;   // 8 * 784 output positions

DEV void async_ld16(const void* g, void* l) {
  __builtin_amdgcn_global_load_lds(
      (const __attribute__((address_space(1))) unsigned int*)g,
      (__attribute__((address_space(3))) unsigned int*)l,
      16, 0, 0);
}

DEV unsigned short f2bf(float x) {
  union { float f; unsigned int u; } v; v.f = x;
  unsigned int u = v.u;
  u += 0x7FFFu + ((u >> 16) & 1u);   // round-to-nearest-even
  return (unsigned short)(u >> 16);
}

DEV float bf2f(unsigned short s) {
  union { unsigned int u; float f; } v; v.u = ((unsigned int)s) << 16;
  return v.f;
}

// ---------------------------------------------------------------------------
// Weight transform: conv_w fp32 [O][C][3][3][3] -> bf16 [tap][o][c]  (B^T)
// ---------------------------------------------------------------------------
__global__ void wtrans(const float* __restrict__ w, unsigned short* __restrict__ wt,
                       int total /* = O*C */) {
  int idx = blockIdx.x * 256 + threadIdx.x;
  if (idx >= total) return;
  const float* src = w + (long)idx * 27;
  #pragma unroll
  for (int tap = 0; tap < 27; ++tap)
    wt[(size_t)tap * total + idx] = f2bf(src[tap]);
}

// ---------------------------------------------------------------------------
// Build P1: videos fp32 [8][1024][14][14] -> P1 bf16 [t=8][s=6][16][16][1024]
// P1[t][s][h+1][w+1][c] = videos[t-5+s][c][h][w] for s in 1..4 (else zero).
// ---------------------------------------------------------------------------
__global__ void build_P1(const float* __restrict__ videos, unsigned short* __restrict__ P1) {
  const int f  = blockIdx.x;
  const int c0 = blockIdx.y * 64;
  const int tid = threadIdx.x;
  __shared__ unsigned short tile[64][196];

  #pragma unroll 1
  for (int it = 0; it < 49; ++it) {       // 49*256 = 64*196 exactly
    int idx = it * 256 + tid;
    int c = idx / 196, r = idx - c * 196;
    tile[c][r] = f2bf(videos[(size_t)(f * 1024 + c0 + c) * 196 + r]);
  }
  __syncthreads();

  const int c   = tid & 63;
  const int hwq = tid >> 6;
  #pragma unroll 1
  for (int s = 1; s <= 4; ++s) {
    int t = f + 5 - s;
    if (t > 7) continue;
    unsigned short* dst = P1 + (size_t)(t * 6 + s) * 256 * 1024 + (size_t)c0;
    #pragma unroll 1
    for (int it = 0; it < 49; ++it) {
      int hw = it * 4 + hwq;
      int h = hw / 14, w = hw - h * 14;
      dst[(size_t)((h + 1) * 16 + (w + 1)) * 1024 + c] = tile[c][hw];
    }
  }
}

// ---------------------------------------------------------------------------
// Implicit-GEMM conv, split-K over taps. 128x128 tile, BK=64, global_load_lds
// x16 with XOR-swizzled segment fetch (zero LDS bank conflicts — R2),
// mfma_f32_16x16x32_bf16. Writes bf16 partial sums.
//
// XCD-locality remap (R3): 1-D grid of 784 blocks; hardware assigns block
// lin -> XCD lin%8. We invert that so XCD j processes cells 98j..98j+97 where
// cell = x*16 + g, g=(y,z). Each XCD owns a contiguous ~6.1-m-tile slab
// (A slab ~4 MB resident in its 4 MB L2) and streams all of B once, tap-
// sequential. Cuts L2-fill traffic ~3x vs round-robin.
//
// A: padded input P [8][6][16][16][CIN] bf16;  B: Wt [27][COUT][CIN] bf16.
// ---------------------------------------------------------------------------
template <int CIN, int COUT, int SLICES>
__global__ __launch_bounds__(256) void conv_gemm(
    const unsigned short* __restrict__ P,
    const unsigned short* __restrict__ Wt,
    unsigned short* __restrict__ part)
{
  __shared__ short lA[128 * 64];
  __shared__ short lB[128 * 64];
  const int tid  = threadIdx.x;
  const int wave = tid >> 6;
  const int lane = tid & 63;

  // lin -> (xcd, q) -> cell -> (m-tile x, group g)
  const int lin = blockIdx.x;
  const int xcd = lin & 7;
  const int q   = lin >> 3;            // 0..97
  const int cell = 98 * xcd + q;       // 0..783
  const int x = cell >> 4;             // 0..48
  const int g = cell & 15;             // NY*SLICES == 16 for both convs
  const int m0 = x * 128;
  const int n0 = (g / SLICES) * 128;
  const int z  = g % SLICES;

  const int tap0 = (27 * z) / SLICES;
  const int tap1 = (27 * (z + 1)) / SLICES;
  unsigned short* partOut = part + (size_t)z * M_TOT * COUT;

  // Staging: LDS segment s_i = i*256+tid (16B units); row r = s_i>>3.
  // XOR swizzle: fetch global segment (tid&7)^(r&7).
  const int rb   = tid >> 3;
  const int segb = (((tid & 7) ^ (rb & 7)) * 16);
  int aoff[4], boff[4];
  #pragma unroll
  for (int i = 0; i < 4; ++i) {
    int r = i * 32 + rb;
    int m = m0 + r;
    int t = m / 784;  int r2 = m - t * 784;
    int d = r2 / 196; int r3 = r2 - d * 196;
    int h = r3 / 14;  int w = r3 - h * 14;
    aoff[i] = ((((t * 6 + d) * 16 + h) * 16 + w) * CIN) * 2 + segb;  // tap-separable
    boff[i] = ((n0 + r) * CIN) * 2 + segb;
  }

  floatx4 acc[4][4];
  const floatx4 zero = {0.f, 0.f, 0.f, 0.f};
  #pragma unroll
  for (int i = 0; i < 4; ++i)
    #pragma unroll
    for (int j = 0; j < 4; ++j) acc[i][j] = zero;

  const char* Pb = (const char*)P;
  const char* Wb = (const char*)Wt;
  const int wm = (wave >> 1) * 64;
  const int wn = (wave & 1) * 64;
  const int quad = lane >> 4;
  const int l15  = lane & 15;
  const int xorv = l15 & 7;

  #pragma unroll 1
  for (int tap = tap0; tap < tap1; ++tap) {
    const int kd = tap / 9; const int rem = tap - kd * 9;
    const int kh = rem / 3; const int kw = rem - kh * 3;
    const int tapA = (((kd * 16) + kh) * 16 + kw) * CIN * 2;
    const int tapB = tap * COUT * CIN * 2;
    #pragma unroll 1
    for (int c0 = 0; c0 < CIN; c0 += 64) {
      const int cb = c0 * 2;
      __syncthreads();
      #pragma unroll
      for (int i = 0; i < 4; ++i)
        async_ld16(Pb + (aoff[i] + tapA + cb), (char*)lA + (i * 256 + tid) * 16);
      #pragma unroll
      for (int i = 0; i < 4; ++i)
        async_ld16(Wb + (boff[i] + tapB + cb), (char*)lB + (i * 256 + tid) * 16);
      __syncthreads();
      #pragma unroll
      for (int ks = 0; ks < 2; ++ks) {
        short8 a[4], b[4];
        #pragma unroll
        for (int i = 0; i < 4; ++i)
          a[i] = *(const short8*)(lA + (wm + i * 16 + l15) * 64 + ((ks * 4 + quad) ^ xorv) * 8);
        #pragma unroll
        for (int j = 0; j < 4; ++j)
          b[j] = *(const short8*)(lB + (wn + j * 16 + l15) * 64 + ((ks * 4 + quad) ^ xorv) * 8);
        #pragma unroll
        for (int i = 0; i < 4; ++i)
          #pragma unroll
          for (int j = 0; j < 4; ++j)
            acc[i][j] = __builtin_amdgcn_mfma_f32_16x16x32_bf16(a[i], b[j], acc[i][j], 0, 0, 0);
      }
    }
  }

  // Epilogue: C/D layout col=lane&15, row=quad*4+reg. Raw bf16 partials.
  #pragma unroll
  for (int j = 0; j < 4; ++j) {
    const int o = n0 + wn + j * 16 + l15;
    #pragma unroll
    for (int i = 0; i < 4; ++i) {
      #pragma unroll
      for (int r = 0; r < 4; ++r) {
        int m = m0 + wm + i * 16 + quad * 4 + r;
        partOut[(size_t)m * COUT + o] = f2bf(acc[i][j][r]);
      }
    }
  }
}

// ---------------------------------------------------------------------------
// reduce1: sum 2 bf16 partial slices + bias, relu, cast bf16, scatter into
// padded P2 layout [8][6][16][16][1024] (interior only; halo pre-zeroed).
// ---------------------------------------------------------------------------
__global__ void reduce_conv1(const unsigned short* __restrict__ part,
                             const float* __restrict__ bias,
                             unsigned short* __restrict__ P2) {
  const int idx = blockIdx.x * 256 + threadIdx.x;
  const int m  = idx >> 8;
  const int o4 = (idx & 255) * 4;
  const size_t base = (size_t)m * 1024 + o4;
  ushort4v p0 = *(const ushort4v*)(part + base);
  ushort4v p1 = *(const ushort4v*)(part + (size_t)M_TOT * 1024 + base);
  ushort4v out;
  #pragma unroll
  for (int k = 0; k < 4; ++k) {
    float v = bf2f(p0[k]) + bf2f(p1[k]) + bias[o4 + k];
    out[k] = f2bf(v > 0.f ? v : 0.f);
  }
  int t = m / 784;  int r2 = m - t * 784;
  int d = r2 / 196; int r3 = r2 - d * 196;
  int h = r3 / 14;  int w = r3 - h * 14;
  size_t didx = (size_t)(((t * 6 + d + 1) * 16 + (h + 1)) * 16 + (w + 1)) * 1024 + o4;
  *(ushort4v*)(P2 + didx) = out;
}

// ---------------------------------------------------------------------------
// reduce2: sum 4 bf16 partial slices + bias, relu, cast bf16 -> h2 [6272][512].
// ---------------------------------------------------------------------------
__global__ void reduce_conv2(const unsigned short* __restrict__ part,
                             const float* __restrict__ bias,
                             unsigned short* __restrict__ h2) {
  const int idx = blockIdx.x * 256 + threadIdx.x;
  const int m  = idx >> 7;
  const int o4 = (idx & 127) * 4;
  const size_t base = (size_t)m * 512 + o4;
  const size_t ss = (size_t)M_TOT * 512;
  ushort4v p0 = *(const ushort4v*)(part + base);
  ushort4v p1 = *(const ushort4v*)(part + ss + base);
  ushort4v p2 = *(const ushort4v*)(part + 2 * ss + base);
  ushort4v p3 = *(const ushort4v*)(part + 3 * ss + base);
  ushort4v out;
  #pragma unroll
  for (int k = 0; k < 4; ++k) {
    float v = bf2f(p0[k]) + bf2f(p1[k]) + bf2f(p2[k]) + bf2f(p3[k]) + bias[o4 + k];
    out[k] = f2bf(v > 0.f ? v : 0.f);
  }
  *(ushort4v*)(h2 + base) = out;
}

// ---------------------------------------------------------------------------
// Max-pool, two-stage (R3: single-stage used only 8 CUs). h2 bf16 >= 0 so
// bf16 bit pattern is monotone -> max raw ushorts. 784 = 28*28.
// ---------------------------------------------------------------------------
__global__ void pool1(const unsigned short* __restrict__ h2,
                      unsigned short* __restrict__ partial) {
  const int t = blockIdx.x / 28, ch = blockIdx.x % 28, o = threadIdx.x;
  const unsigned short* src = h2 + ((size_t)t * 784 + ch * 28) * 512 + o;
  unsigned short m = 0;
  #pragma unroll 4
  for (int i = 0; i < 28; ++i) { unsigned short v = src[(size_t)i * 512]; m = v > m ? v : m; }
  partial[((size_t)t * 28 + ch) * 512 + o] = m;
}

__global__ void pool2(const unsigned short* __restrict__ partial, float* __restrict__ pooled) {
  const int t = blockIdx.x, o = threadIdx.x;
  const unsigned short* src = partial + (size_t)t * 28 * 512 + o;
  unsigned short m = 0;
  #pragma unroll 4
  for (int i = 0; i < 28; ++i) { unsigned short v = src[(size_t)i * 512]; m = v > m ? v : m; }
  pooled[t * 512 + o] = bf2f(m);
}

// ---------------------------------------------------------------------------
// Tiny MLP, fp32. Block per t, 512 threads.
// ---------------------------------------------------------------------------
__global__ void mlp_kernel(const float* __restrict__ pooled,
                           const float* __restrict__ w1, const float* __restrict__ b1,
                           const float* __restrict__ w2, const float* __restrict__ b2,
                           const float* __restrict__ w3, const float* __restrict__ b3,
                           float* __restrict__ out) {
  const int t = blockIdx.x, j = threadIdx.x;
  __shared__ float xa[512], xb[512];
  xa[j] = pooled[t * 512 + j];
  __syncthreads();
  {
    const float4* wr = (const float4*)(w1 + (size_t)j * 512);
    float s = b1[j];
    #pragma unroll 4
    for (int k = 0; k < 128; ++k) {
      float4 wv = wr[k];
      s += wv.x * xa[4*k] + wv.y * xa[4*k+1] + wv.z * xa[4*k+2] + wv.w * xa[4*k+3];
    }
    xb[j] = fmaxf(s, 0.f);
  }
  __syncthreads();
  {
    const float4* wr = (const float4*)(w2 + (size_t)j * 512);
    float s = b2[j];
    #pragma unroll 4
    for (int k = 0; k < 128; ++k) {
      float4 wv = wr[k];
      s += wv.x * xb[4*k] + wv.y * xb[4*k+1] + wv.z * xb[4*k+2] + wv.w * xb[4*k+3];
    }
    xa[j] = fmaxf(s, 0.f);
  }
  __syncthreads();
  if (j < 128) {
    const float4* wr = (const float4*)(w3 + (size_t)j * 512);
    float s = b3[j];
    #pragma unroll 4
    for (int k = 0; k < 128; ++k) {
      float4 wv = wr[k];
      s += wv.x * xa[4*k] + wv.y * xa[4*k+1] + wv.z * xa[4*k+2] + wv.w * xa[4*k+3];
    }
    out[t * 128 + j] = fmaxf(s, 0.f);
  }
}

// ---------------------------------------------------------------------------
// Workspace layout (bytes) — total ~142.5 MB:
//   P1/P2 (aliased) @ 0          : 8*6*16*16*1024*2 = 25,165,824
//   W1t             @ 25165824   : 27*1024*1024*2   = 56,623,104
//   W2t             @ 81788928   : 27*512*1024*2    = 28,311,552
//   part (reused)   @ 110100480  : 25,690,112
//   h2 bf16         @ 135790592  : 6,422,528
//   pooled          @ 142213120  : 16,384
//   pool partial    @ 142229504  : 8*28*512*2 = 229,376
// ---------------------------------------------------------------------------
extern "C" void kernel_launch(void* const* d_in, const int* in_sizes, int n_in,
                              void* d_out, int out_size, void* d_ws, size_t ws_size,
                              hipStream_t stream) {
  const float* videos = (const float*)d_in[0];
  const float* c1w = (const float*)d_in[1];
  const float* c1b = (const float*)d_in[2];
  const float* c2w = (const float*)d_in[3];
  const float* c2b = (const float*)d_in[4];
  const float* l1w = (const float*)d_in[5];
  const float* l1b = (const float*)d_in[6];
  const float* l2w = (const float*)d_in[7];
  const float* l2b = (const float*)d_in[8];
  const float* l3w = (const float*)d_in[9];
  const float* l3b = (const float*)d_in[10];

  char* ws = (char*)d_ws;
  unsigned short* P12 = (unsigned short*)(ws);               // P1, later P2
  unsigned short* W1t = (unsigned short*)(ws + 25165824);
  unsigned short* W2t = (unsigned short*)(ws + 81788928);
  unsigned short* part = (unsigned short*)(ws + 110100480);
  unsigned short* h2  = (unsigned short*)(ws + 135790592);
  float* pooled = (float*)(ws + 142213120);
  unsigned short* ppart = (unsigned short*)(ws + 142229504);
  float* out = (float*)d_out;

  // Zero the padded activation buffer (halo + unused windows must be 0).
  hipMemsetAsync(ws, 0, 25165824, stream);

  wtrans<<<4096, 256, 0, stream>>>(c1w, W1t, 1024 * 1024);
  wtrans<<<2048, 256, 0, stream>>>(c2w, W2t, 512 * 1024);
  build_P1<<<dim3(8, 16), 256, 0, stream>>>(videos, P12);

  conv_gemm<1024, 1024, 2><<<784, 256, 0, stream>>>(P12, W1t, part);
  reduce_conv1<<<6272, 256, 0, stream>>>(part, c1b, P12);
  conv_gemm<1024, 512, 4><<<784, 256, 0, stream>>>(P12, W2t, part);
  reduce_conv2<<<3136, 256, 0, stream>>>(part, c2b, h2);

  pool1<<<224, 512, 0, stream>>>(h2, ppart);
  pool2<<<8, 512, 0, stream>>>(ppart, pooled);
  mlp_kernel<<<8, 512, 0, stream>>>(pooled, l1w, l1b, l2w, l2b, l3w, l3b, out);
}

// Round 5
// 863.031 us; speedup vs baseline: 1.8482x; 1.2097x over previous
//
#include <hip/hip_runtime.h>

typedef __attribute__((ext_vector_type(8))) short short8;
typedef __attribute__((ext_vector_type(4))) float floatx4;
typedef __attribute__((ext_vector_type(4))) unsigned short ushort4v;

#define DEV __device__ __forceinline__

constexpr int M_TOT = 6272;   // 8 * 784 output positions

DEV void async_ld16(const void* g, void* l) {
  __builtin_amdgcn_global_load_lds(
      (const __attribute__((address_space(1))) unsigned int*)g,
      (__attribute__((address_space(3))) unsigned int*)l,
      16, 0, 0);
}

DEV unsigned short f2bf(float x) {
  union { float f; unsigned int u; } v; v.f = x;
  unsigned int u = v.u;
  u += 0x7FFFu + ((u >> 16) & 1u);   // round-to-nearest-even
  return (unsigned short)(u >> 16);
}

DEV float bf2f(unsigned short s) {
  union { unsigned int u; float f; } v; v.u = ((unsigned int)s) << 16;
  return v.f;
}

// ---------------------------------------------------------------------------
// Weight transform: conv_w fp32 [O][C][3][3][3] -> bf16 [tap][o][c]  (B^T).
// R5: LDS transpose — coalesced reads (was stride-27) and coalesced writes.
// ---------------------------------------------------------------------------
__global__ void wtrans(const float* __restrict__ w, unsigned short* __restrict__ wt,
                       int total /* = O*C, multiple of 256 */) {
  __shared__ unsigned short l[256 * 27];
  const int tid  = threadIdx.x;
  const int base = blockIdx.x * 256;
  #pragma unroll 1
  for (int j = tid; j < 256 * 27; j += 256)
    l[j] = f2bf(w[(size_t)base * 27 + j]);
  __syncthreads();
  #pragma unroll 1
  for (int tap = 0; tap < 27; ++tap)
    wt[(size_t)tap * total + base + tid] = l[tid * 27 + tap];
}

// ---------------------------------------------------------------------------
// Build P1: videos fp32 [8][1024][14][14] -> P1 bf16 [t=8][s=6][16][16][1024]
// P1[t][s][h+1][w+1][c] = videos[t-5+s][c][h][w] for s in 1..4 (else zero).
// ---------------------------------------------------------------------------
__global__ void build_P1(const float* __restrict__ videos, unsigned short* __restrict__ P1) {
  const int f  = blockIdx.x;
  const int c0 = blockIdx.y * 64;
  const int tid = threadIdx.x;
  __shared__ unsigned short tile[64][196];

  #pragma unroll 1
  for (int it = 0; it < 49; ++it) {       // 49*256 = 64*196 exactly
    int idx = it * 256 + tid;
    int c = idx / 196, r = idx - c * 196;
    tile[c][r] = f2bf(videos[(size_t)(f * 1024 + c0 + c) * 196 + r]);
  }
  __syncthreads();

  const int c   = tid & 63;
  const int hwq = tid >> 6;
  #pragma unroll 1
  for (int s = 1; s <= 4; ++s) {
    int t = f + 5 - s;
    if (t > 7) continue;
    unsigned short* dst = P1 + (size_t)(t * 6 + s) * 256 * 1024 + (size_t)c0;
    #pragma unroll 1
    for (int it = 0; it < 49; ++it) {
      int hw = it * 4 + hwq;
      int h = hw / 14, w = hw - h * 14;
      dst[(size_t)((h + 1) * 16 + (w + 1)) * 1024 + c] = tile[c][hw];
    }
  }
}

// ---------------------------------------------------------------------------
// Implicit-GEMM conv, split-K over taps. 128x128 tile, BK=64, global_load_lds
// x16 with XOR-swizzled segment fetch (zero LDS bank conflicts — R2),
// mfma_f32_16x16x32_bf16. Writes bf16 partial sums.
//
// R5: (a) structural tap skipping — depth-tap kd is skipped when slice
// s=d+kd is zero (outside 1..4, or frame t-5+s < 0 for conv1) for ALL rows
// of the tile; skipped taps contributed exact 0.0 before, so results are
// bit-identical. conv1 keeps 67.3% of taps, conv2 93%.
// (b) host-balanced cell permutation (perm[lin], lin%8 = XCD bin) so the
// skip savings are spread evenly over XCDs (any bijection is correct).
//
// A: padded input P [8][6][16][16][CIN] bf16;  B: Wt [27][COUT][CIN] bf16.
// ---------------------------------------------------------------------------
template <int CIN, int COUT, int SLICES, bool TCOND>
__global__ __launch_bounds__(256) void conv_gemm(
    const unsigned short* __restrict__ P,
    const unsigned short* __restrict__ Wt,
    const unsigned short* __restrict__ perm,
    unsigned short* __restrict__ part)
{
  __shared__ short lA[128 * 64];
  __shared__ short lB[128 * 64];
  const int tid  = threadIdx.x;
  const int wave = tid >> 6;
  const int lane = tid & 63;

  const int cell = perm[blockIdx.x];
  const int x = cell >> 4;             // 0..48
  const int g = cell & 15;             // NY*SLICES == 16 for both convs
  const int m0 = x * 128;
  const int n0 = (g / SLICES) * 128;
  const int z  = g % SLICES;

  const int tap0 = (27 * z) / SLICES;
  const int tap1 = (27 * (z + 1)) / SLICES;
  unsigned short* partOut = part + (size_t)z * M_TOT * COUT;

  // Tile-level depth-tap validity. Tile rows span <=2 (t,d) cells of 196 rows.
  bool kdv[3];
  {
    const int c1 = m0 / 196, c2 = (m0 + 127) / 196;
    #pragma unroll
    for (int kd = 0; kd < 3; ++kd) {
      bool v = false;
      #pragma unroll
      for (int ci = 0; ci < 2; ++ci) {
        int c = ci ? c2 : c1;
        if (ci && c2 == c1) continue;
        int t = c >> 2, d = c & 3, s = d + kd;
        bool ok = (s >= 1) && (s <= 4);
        if (TCOND) ok = ok && (s >= 5 - t);
        v = v || ok;
      }
      kdv[kd] = v;
    }
  }

  // Staging: LDS segment s_i = i*256+tid (16B units); row r = s_i>>3.
  // XOR swizzle: fetch global segment (tid&7)^(r&7).
  const int rb   = tid >> 3;
  const int segb = (((tid & 7) ^ (rb & 7)) * 16);
  int aoff[4], boff[4];
  #pragma unroll
  for (int i = 0; i < 4; ++i) {
    int r = i * 32 + rb;
    int m = m0 + r;
    int t = m / 784;  int r2 = m - t * 784;
    int d = r2 / 196; int r3 = r2 - d * 196;
    int h = r3 / 14;  int w = r3 - h * 14;
    aoff[i] = ((((t * 6 + d) * 16 + h) * 16 + w) * CIN) * 2 + segb;  // tap-separable
    boff[i] = ((n0 + r) * CIN) * 2 + segb;
  }

  floatx4 acc[4][4];
  const floatx4 zero = {0.f, 0.f, 0.f, 0.f};
  #pragma unroll
  for (int i = 0; i < 4; ++i)
    #pragma unroll
    for (int j = 0; j < 4; ++j) acc[i][j] = zero;

  const char* Pb = (const char*)P;
  const char* Wb = (const char*)Wt;
  const int wm = (wave >> 1) * 64;
  const int wn = (wave & 1) * 64;
  const int quad = lane >> 4;
  const int l15  = lane & 15;
  const int xorv = l15 & 7;

  #pragma unroll 1
  for (int tap = tap0; tap < tap1; ++tap) {
    if (!kdv[tap / 9]) continue;       // whole-tile-zero depth tap: exact skip
    const int kd = tap / 9; const int rem = tap - kd * 9;
    const int kh = rem / 3; const int kw = rem - kh * 3;
    const int tapA = (((kd * 16) + kh) * 16 + kw) * CIN * 2;
    const int tapB = tap * COUT * CIN * 2;
    #pragma unroll 1
    for (int c0 = 0; c0 < CIN; c0 += 64) {
      const int cb = c0 * 2;
      __syncthreads();
      #pragma unroll
      for (int i = 0; i < 4; ++i)
        async_ld16(Pb + (aoff[i] + tapA + cb), (char*)lA + (i * 256 + tid) * 16);
      #pragma unroll
      for (int i = 0; i < 4; ++i)
        async_ld16(Wb + (boff[i] + tapB + cb), (char*)lB + (i * 256 + tid) * 16);
      __syncthreads();
      #pragma unroll
      for (int ks = 0; ks < 2; ++ks) {
        short8 a[4], b[4];
        #pragma unroll
        for (int i = 0; i < 4; ++i)
          a[i] = *(const short8*)(lA + (wm + i * 16 + l15) * 64 + ((ks * 4 + quad) ^ xorv) * 8);
        #pragma unroll
        for (int j = 0; j < 4; ++j)
          b[j] = *(const short8*)(lB + (wn + j * 16 + l15) * 64 + ((ks * 4 + quad) ^ xorv) * 8);
        #pragma unroll
        for (int i = 0; i < 4; ++i)
          #pragma unroll
          for (int j = 0; j < 4; ++j)
            acc[i][j] = __builtin_amdgcn_mfma_f32_16x16x32_bf16(a[i], b[j], acc[i][j], 0, 0, 0);
      }
    }
  }

  // Epilogue: C/D layout col=lane&15, row=quad*4+reg. Raw bf16 partials.
  #pragma unroll
  for (int j = 0; j < 4; ++j) {
    const int o = n0 + wn + j * 16 + l15;
    #pragma unroll
    for (int i = 0; i < 4; ++i) {
      #pragma unroll
      for (int r = 0; r < 4; ++r) {
        int m = m0 + wm + i * 16 + quad * 4 + r;
        partOut[(size_t)m * COUT + o] = f2bf(acc[i][j][r]);
      }
    }
  }
}

// ---------------------------------------------------------------------------
// reduce1: sum 2 bf16 partial slices + bias, relu, cast bf16, scatter into
// padded P2 layout [8][6][16][16][1024] (interior only; halo pre-zeroed).
// ---------------------------------------------------------------------------
__global__ void reduce_conv1(const unsigned short* __restrict__ part,
                             const float* __restrict__ bias,
                             unsigned short* __restrict__ P2) {
  const int idx = blockIdx.x * 256 + threadIdx.x;
  const int m  = idx >> 8;
  const int o4 = (idx & 255) * 4;
  const size_t base = (size_t)m * 1024 + o4;
  ushort4v p0 = *(const ushort4v*)(part + base);
  ushort4v p1 = *(const ushort4v*)(part + (size_t)M_TOT * 1024 + base);
  ushort4v out;
  #pragma unroll
  for (int k = 0; k < 4; ++k) {
    float v = bf2f(p0[k]) + bf2f(p1[k]) + bias[o4 + k];
    out[k] = f2bf(v > 0.f ? v : 0.f);
  }
  int t = m / 784;  int r2 = m - t * 784;
  int d = r2 / 196; int r3 = r2 - d * 196;
  int h = r3 / 14;  int w = r3 - h * 14;
  size_t didx = (size_t)(((t * 6 + d + 1) * 16 + (h + 1)) * 16 + (w + 1)) * 1024 + o4;
  *(ushort4v*)(P2 + didx) = out;
}

// ---------------------------------------------------------------------------
// reduce2: sum 4 bf16 partial slices + bias, relu, cast bf16 -> h2 [6272][512].
// ---------------------------------------------------------------------------
__global__ void reduce_conv2(const unsigned short* __restrict__ part,
                             const float* __restrict__ bias,
                             unsigned short* __restrict__ h2) {
  const int idx = blockIdx.x * 256 + threadIdx.x;
  const int m  = idx >> 7;
  const int o4 = (idx & 127) * 4;
  const size_t base = (size_t)m * 512 + o4;
  const size_t ss = (size_t)M_TOT * 512;
  ushort4v p0 = *(const ushort4v*)(part + base);
  ushort4v p1 = *(const ushort4v*)(part + ss + base);
  ushort4v p2 = *(const ushort4v*)(part + 2 * ss + base);
  ushort4v p3 = *(const ushort4v*)(part + 3 * ss + base);
  ushort4v out;
  #pragma unroll
  for (int k = 0; k < 4; ++k) {
    float v = bf2f(p0[k]) + bf2f(p1[k]) + bf2f(p2[k]) + bf2f(p3[k]) + bias[o4 + k];
    out[k] = f2bf(v > 0.f ? v : 0.f);
  }
  *(ushort4v*)(h2 + base) = out;
}

// ---------------------------------------------------------------------------
// Max-pool, two-stage. h2 bf16 >= 0 -> bit pattern monotone -> max raw ushorts.
// ---------------------------------------------------------------------------
__global__ void pool1(const unsigned short* __restrict__ h2,
                      unsigned short* __restrict__ partial) {
  const int t = blockIdx.x / 28, ch = blockIdx.x % 28, o = threadIdx.x;
  const unsigned short* src = h2 + ((size_t)t * 784 + ch * 28) * 512 + o;
  unsigned short m = 0;
  #pragma unroll 4
  for (int i = 0; i < 28; ++i) { unsigned short v = src[(size_t)i * 512]; m = v > m ? v : m; }
  partial[((size_t)t * 28 + ch) * 512 + o] = m;
}

__global__ void pool2(const unsigned short* __restrict__ partial, float* __restrict__ pooled) {
  const int t = blockIdx.x, o = threadIdx.x;
  const unsigned short* src = partial + (size_t)t * 28 * 512 + o;
  unsigned short m = 0;
  #pragma unroll 4
  for (int i = 0; i < 28; ++i) { unsigned short v = src[(size_t)i * 512]; m = v > m ? v : m; }
  pooled[t * 512 + o] = bf2f(m);
}

// ---------------------------------------------------------------------------
// Tiny MLP, fp32. Block per t, 512 threads.
// ---------------------------------------------------------------------------
__global__ void mlp_kernel(const float* __restrict__ pooled,
                           const float* __restrict__ w1, const float* __restrict__ b1,
                           const float* __restrict__ w2, const float* __restrict__ b2,
                           const float* __restrict__ w3, const float* __restrict__ b3,
                           float* __restrict__ out) {
  const int t = blockIdx.x, j = threadIdx.x;
  __shared__ float xa[512], xb[512];
  xa[j] = pooled[t * 512 + j];
  __syncthreads();
  {
    const float4* wr = (const float4*)(w1 + (size_t)j * 512);
    float s = b1[j];
    #pragma unroll 4
    for (int k = 0; k < 128; ++k) {
      float4 wv = wr[k];
      s += wv.x * xa[4*k] + wv.y * xa[4*k+1] + wv.z * xa[4*k+2] + wv.w * xa[4*k+3];
    }
    xb[j] = fmaxf(s, 0.f);
  }
  __syncthreads();
  {
    const float4* wr = (const float4*)(w2 + (size_t)j * 512);
    float s = b2[j];
    #pragma unroll 4
    for (int k = 0; k < 128; ++k) {
      float4 wv = wr[k];
      s += wv.x * xb[4*k] + wv.y * xb[4*k+1] + wv.z * xb[4*k+2] + wv.w * xb[4*k+3];
    }
    xa[j] = fmaxf(s, 0.f);
  }
  __syncthreads();
  if (j < 128) {
    const float4* wr = (const float4*)(w3 + (size_t)j * 512);
    float s = b3[j];
    #pragma unroll 4
    for (int k = 0; k < 128; ++k) {
      float4 wv = wr[k];
      s += wv.x * xa[4*k] + wv.y * xa[4*k+1] + wv.z * xa[4*k+2] + wv.w * xa[4*k+3];
    }
    out[t * 128 + j] = fmaxf(s, 0.f);
  }
}

// ---------------------------------------------------------------------------
// Host-side work-balanced permutation. Any bijection 0..783 is CORRECT; this
// one equalizes per-XCD tap work under structural skipping, keeping the 16
// cells of an m-tile on one XCD where possible (L2 locality, R4 win).
// ---------------------------------------------------------------------------
static void compute_perm(int SLICES, bool tcond, unsigned short* perm) {
  auto cellValid = [&](int c, int kd) -> bool {
    int t = c >> 2, d = c & 3, s = d + kd;
    if (s < 1 || s > 4) return false;
    if (tcond && s < 5 - t) return false;
    return true;
  };
  int wxz[49][4]; int Wx[49];
  for (int x = 0; x < 49; ++x) {
    int m0 = x * 128;
    int c1 = m0 / 196, c2 = (m0 + 127) / 196;
    bool kdv[3];
    for (int kd = 0; kd < 3; ++kd)
      kdv[kd] = cellValid(c1, kd) || (c2 != c1 && cellValid(c2, kd));
    Wx[x] = 0;
    for (int z = 0; z < SLICES; ++z) {
      int t0 = (27 * z) / SLICES, t1 = (27 * (z + 1)) / SLICES, cnt = 0;
      for (int tap = t0; tap < t1; ++tap) if (kdv[tap / 9]) ++cnt;
      wxz[x][z] = cnt; Wx[x] += cnt;
    }
  }
  int order[49];
  for (int i = 0; i < 49; ++i) order[i] = i;
  for (int i = 0; i < 49; ++i)
    for (int j = i + 1; j < 49; ++j)
      if (Wx[order[j]] > Wx[order[i]]) { int t = order[i]; order[i] = order[j]; order[j] = t; }
  int binw[8] = {0, 0, 0, 0, 0, 0, 0, 0}, binn[8] = {0, 0, 0, 0, 0, 0, 0, 0};
  unsigned short cells[8][98];
  for (int oi = 0; oi < 49; ++oi) {
    int x = order[oi];
    int best = -1;
    for (int b = 0; b < 8; ++b)
      if (binn[b] + 16 <= 98 && (best < 0 || binw[b] < binw[best])) best = b;
    if (best >= 0) {
      for (int g = 0; g < 16; ++g) cells[best][binn[best]++] = (unsigned short)(x * 16 + g);
      binw[best] += Wx[x];
    } else {
      for (int g = 0; g < 16; ++g) {
        int z = g % SLICES; int bb = -1;
        for (int b = 0; b < 8; ++b)
          if (binn[b] < 98 && (bb < 0 || binw[b] < binw[bb])) bb = b;
        cells[bb][binn[bb]++] = (unsigned short)(x * 16 + g);
        binw[bb] += wxz[x][z];
      }
    }
  }
  for (int b = 0; b < 8; ++b) {
    for (int i = 0; i < 98; ++i)
      for (int j = i + 1; j < 98; ++j)
        if (cells[b][j] < cells[b][i]) { unsigned short t = cells[b][i]; cells[b][i] = cells[b][j]; cells[b][j] = t; }
    for (int q = 0; q < 98; ++q) perm[q * 8 + b] = cells[b][q];
  }
}

// ---------------------------------------------------------------------------
// Workspace layout (bytes) — total ~142.5 MB:
//   P1/P2 (aliased) @ 0          : 8*6*16*16*1024*2 = 25,165,824
//   W1t             @ 25165824   : 27*1024*1024*2   = 56,623,104
//   W2t             @ 81788928   : 27*512*1024*2    = 28,311,552
//   part (reused)   @ 110100480  : 25,690,112
//   h2 bf16         @ 135790592  : 6,422,528
//   pooled          @ 142213120  : 16,384
//   pool partial    @ 142229504  : 229,376
//   perm1           @ 142458880  : 1,568
//   perm2           @ 142460448  : 1,568
// ---------------------------------------------------------------------------
extern "C" void kernel_launch(void* const* d_in, const int* in_sizes, int n_in,
                              void* d_out, int out_size, void* d_ws, size_t ws_size,
                              hipStream_t stream) {
  const float* videos = (const float*)d_in[0];
  const float* c1w = (const float*)d_in[1];
  const float* c1b = (const float*)d_in[2];
  const float* c2w = (const float*)d_in[3];
  const float* c2b = (const float*)d_in[4];
  const float* l1w = (const float*)d_in[5];
  const float* l1b = (const float*)d_in[6];
  const float* l2w = (const float*)d_in[7];
  const float* l2b = (const float*)d_in[8];
  const float* l3w = (const float*)d_in[9];
  const float* l3b = (const float*)d_in[10];

  char* ws = (char*)d_ws;
  unsigned short* P12 = (unsigned short*)(ws);               // P1, later P2
  unsigned short* W1t = (unsigned short*)(ws + 25165824);
  unsigned short* W2t = (unsigned short*)(ws + 81788928);
  unsigned short* part = (unsigned short*)(ws + 110100480);
  unsigned short* h2  = (unsigned short*)(ws + 135790592);
  float* pooled = (float*)(ws + 142213120);
  unsigned short* ppart = (unsigned short*)(ws + 142229504);
  unsigned short* dperm1 = (unsigned short*)(ws + 142458880);
  unsigned short* dperm2 = (unsigned short*)(ws + 142460448);
  float* out = (float*)d_out;

  // Host perms: static so the captured memcpy node's source persists across
  // graph replays; recomputed identically every call (no call-count guards).
  static unsigned short perm1_h[784], perm2_h[784];
  compute_perm(2, true,  perm1_h);
  compute_perm(4, false, perm2_h);
  hipMemcpyAsync(dperm1, perm1_h, sizeof(perm1_h), hipMemcpyHostToDevice, stream);
  hipMemcpyAsync(dperm2, perm2_h, sizeof(perm2_h), hipMemcpyHostToDevice, stream);

  // Zero the padded activation buffer (halo + unused windows must be 0).
  hipMemsetAsync(ws, 0, 25165824, stream);

  wtrans<<<4096, 256, 0, stream>>>(c1w, W1t, 1024 * 1024);
  wtrans<<<2048, 256, 0, stream>>>(c2w, W2t, 512 * 1024);
  build_P1<<<dim3(8, 16), 256, 0, stream>>>(videos, P12);

  conv_gemm<1024, 1024, 2, true ><<<784, 256, 0, stream>>>(P12, W1t, dperm1, part);
  reduce_conv1<<<6272, 256, 0, stream>>>(part, c1b, P12);
  conv_gemm<1024, 512, 4, false><<<784, 256, 0, stream>>>(P12, W2t, dperm2, part);
  reduce_conv2<<<3136, 256, 0, stream>>>(part, c2b, h2);

  pool1<<<224, 512, 0, stream>>>(h2, ppart);
  pool2<<<8, 512, 0, stream>>>(ppart, pooled);
  mlp_kernel<<<8, 512, 0, stream>>>(pooled, l1w, l1b, l2w, l2b, l3w, l3b, out);
}